// Round 6
// baseline (124.703 us; speedup 1.0000x reference)
//
#include <hip/hip_runtime.h>
#include <hip/hip_bf16.h>

// loss = (100/N^2) * [3*s_tt + s_rr + s_dd + s_ii - 2*(s_tr + s_td + s_ti)]
// where s_ab = || n_a^T n_b ||_F^2   (n_x = row-normalized input, N=4096, D=512)
//
// fp8 pipeline, 2 dispatches total (no memset, no split-K, no Cbuf, no reduce):
// K1 preprocess: fused rownorm + scale(16/||r||) + fp8 cast + transpose
//                -> nT8[mod][c][k] (8 MB, K-contiguous); also zeroes d_out
// K2 gram:       7 TN-GEMMs 512x512 fp8, 112 blocks x 512 thr, 128x128 tile,
//                full K=4096 per block (32 chunks of 128, dbuf LDS, XOR
//                swizzle, b128 conflict-free frag reads), LOCAL Frobenius
//                square -> ONE scalar atomicAdd per block.
// Frobenius structure => immune to any consistent K-permutation and to the
// MFMA C/D layout; x16 pre-scale folded into normalization, /16^4 at the end.

typedef __attribute__((ext_vector_type(4))) float floatx4;
typedef __attribute__((ext_vector_type(8))) unsigned short ushort8;
typedef __attribute__((ext_vector_type(2))) long long llx2;

#define N_ROWS 4096
#define DDIM   512
// 100 / (4096^2 * 16^4)
#define LOSS_SCALE 9.094947017729282e-11f

__device__ __forceinline__ const float* sel_mod(int mod, const float* a,
                                                const float* b, const float* c,
                                                const float* d) {
  return mod == 0 ? a : mod == 1 ? b : mod == 2 ? c : d;
}

__global__ __launch_bounds__(256) void preprocess_kernel(
    const float* __restrict__ in0, const float* __restrict__ in1,
    const float* __restrict__ in2, const float* __restrict__ in3,
    unsigned char* __restrict__ nT8, float* __restrict__ out) {
  // grid: x = 64 (k-strips of 64 rows), y = 4 (mod). 256 threads = 4 waves.
  int mod = blockIdx.y;
  int k0 = blockIdx.x * 64;
  const float* X = sel_mod(mod, in0, in1, in2, in3) + (size_t)k0 * DDIM;

  if (blockIdx.x == 0 && blockIdx.y == 0 && threadIdx.x == 0)
    out[0] = 0.f;  // d_out is re-poisoned before every call; gram accumulates

  __shared__ float rsc[64];
  __shared__ unsigned short tile[128][72];  // bf16 intermediate, 16B-aligned

  int t = threadIdx.x;
  int w = t >> 6, lane = t & 63;

  // phase A: row norms for this strip (16 rows per wave)
#pragma unroll
  for (int i = 0; i < 16; ++i) {
    int r = w * 16 + i;
    const float4* rp = (const float4*)(X + (size_t)r * DDIM);
    float4 a = rp[lane];
    float4 b = rp[lane + 64];
    float ss = a.x * a.x + a.y * a.y + a.z * a.z + a.w * a.w +
               b.x * b.x + b.y * b.y + b.z * b.z + b.w * b.w;
#pragma unroll
    for (int off = 32; off > 0; off >>= 1) ss += __shfl_down(ss, off, 64);
    if (lane == 0) rsc[r] = 16.0f / fmaxf(sqrtf(ss), 1e-12f);  // x16 folded
  }
  __syncthreads();

  // phase B: 4 panels of 128 cols; rows re-read from L2
  for (int p = 0; p < 4; ++p) {
#pragma unroll
    for (int it = 0; it < 8; ++it) {
      int idx = it * 256 + t;
      int r = idx >> 5;          // k-row 0..63
      int c4 = idx & 31;         // float4 index within 128-col panel
      float4 v = ((const float4*)(X + (size_t)r * DDIM + p * 128))[c4];
      float sc = rsc[r];
      __hip_bfloat16 h0 = __float2bfloat16(v.x * sc);
      __hip_bfloat16 h1 = __float2bfloat16(v.y * sc);
      __hip_bfloat16 h2 = __float2bfloat16(v.z * sc);
      __hip_bfloat16 h3 = __float2bfloat16(v.w * sc);
      tile[c4 * 4 + 0][r] = *(unsigned short*)&h0;
      tile[c4 * 4 + 1][r] = *(unsigned short*)&h1;
      tile[c4 * 4 + 2][r] = *(unsigned short*)&h2;
      tile[c4 * 4 + 3][r] = *(unsigned short*)&h3;
    }
    __syncthreads();
#pragma unroll
    for (int it = 0; it < 2; ++it) {
      int idx = it * 256 + t;
      int c = idx >> 2;          // column 0..127
      int g = idx & 3;           // 16-byte k-group
      ushort8 u0 = *(const ushort8*)&tile[c][g * 16];
      ushort8 u1 = *(const ushort8*)&tile[c][g * 16 + 8];
      float f[16];
#pragma unroll
      for (int j = 0; j < 8; ++j) {
        f[j] = __uint_as_float(((unsigned int)(unsigned short)u0[j]) << 16);
        f[8 + j] = __uint_as_float(((unsigned int)(unsigned short)u1[j]) << 16);
      }
      unsigned int wds[4];
#pragma unroll
      for (int q = 0; q < 4; ++q) {
        unsigned int pk =
            __builtin_amdgcn_cvt_pk_fp8_f32(f[4 * q], f[4 * q + 1], 0, 0);
        pk = __builtin_amdgcn_cvt_pk_fp8_f32(f[4 * q + 2], f[4 * q + 3], pk, 1);
        wds[q] = pk;  // byte order is a fixed uniform k-perm: harmless
      }
      uint4 o = {wds[0], wds[1], wds[2], wds[3]};
      *(uint4*)(nT8 + ((size_t)(mod * DDIM + p * 128 + c)) * N_ROWS + k0 +
                g * 16) = o;
    }
    __syncthreads();
  }
}

__device__ __forceinline__ void stage_tiles(
    const unsigned char* __restrict__ Abase,
    const unsigned char* __restrict__ Bbase, int k0,
    unsigned char* lsA, unsigned char* lsB, int w, int lane) {
  // 16B-chunk XOR swizzle: LDS slot s of row r holds global chunk s^((r>>1)&7)
  int rr = lane >> 3;          // row 0..7 within the 8-row staging group
  int s = lane & 7;            // 16B slot within 128B row
#pragma unroll
  for (int c = 0; c < 2; ++c) {
    int base = w * 16 + c * 8;  // wave-uniform; 8 waves x 2 x 8 rows = 128
    int row = base + rr;
    int gc = s ^ ((row >> 1) & 7);
    const unsigned char* ga = Abase + (size_t)row * N_ROWS + k0 + gc * 16;
    const unsigned char* gb = Bbase + (size_t)row * N_ROWS + k0 + gc * 16;
    __builtin_amdgcn_global_load_lds(
        (__attribute__((address_space(1))) void*)(void*)ga,
        (__attribute__((address_space(3))) void*)(void*)&lsA[base * 128],
        16, 0, 0);
    __builtin_amdgcn_global_load_lds(
        (__attribute__((address_space(1))) void*)(void*)gb,
        (__attribute__((address_space(3))) void*)(void*)&lsB[base * 128],
        16, 0, 0);
  }
}

__device__ __forceinline__ void compute_tiles(
    const unsigned char* lsA, const unsigned char* lsB,
    floatx4 acc[4][2], int wr, int wc, int lm, int lq) {
  // Lane lq's 4 K-steps live in LDS slots lq*2 and lq*2+1 (after unswizzle):
  // two b128 reads per fragment row, uniform 2 lanes/bank (conflict-free).
  // (ks,lq) -> global K-unit lq*4 + (ks>>1)*2 + (ks&1): a uniform K-perm
  // applied identically to A and B => Frobenius-invariant.
  llx2 A16[4][2], B16[2][2];
#pragma unroll
  for (int mi = 0; mi < 4; ++mi) {
    int row = wr + mi * 16 + lm;
    int sw = (row >> 1) & 7;
    A16[mi][0] = *(const llx2*)&lsA[row * 128 + ((lq * 2) ^ sw) * 16];
    A16[mi][1] = *(const llx2*)&lsA[row * 128 + ((lq * 2 + 1) ^ sw) * 16];
  }
#pragma unroll
  for (int ni = 0; ni < 2; ++ni) {
    int row = wc + ni * 16 + lm;
    int sw = (row >> 1) & 7;
    B16[ni][0] = *(const llx2*)&lsB[row * 128 + ((lq * 2) ^ sw) * 16];
    B16[ni][1] = *(const llx2*)&lsB[row * 128 + ((lq * 2 + 1) ^ sw) * 16];
  }
#pragma unroll
  for (int ks = 0; ks < 4; ++ks) {
    int h = ks >> 1, e = ks & 1;
#pragma unroll
    for (int mi = 0; mi < 4; ++mi)
#pragma unroll
      for (int ni = 0; ni < 2; ++ni)
        acc[mi][ni] = __builtin_amdgcn_mfma_f32_16x16x32_fp8_fp8(
            A16[mi][h][e], B16[ni][h][e], acc[mi][ni], 0, 0, 0);
  }
}

__global__ __launch_bounds__(512) void gram_frob_kernel(
    const unsigned char* __restrict__ nT8, float* __restrict__ out) {
  // blockIdx: x = tile 0..15 (4x4 over 512x512), y = product 0..6
  __shared__ unsigned char ls[2][2][128 * 128];  // [buf][A/B], 64 KB
  __shared__ float red[8];

  const int   pa[7] = {3, 0, 1, 2, 3, 3, 3};
  const int   pb[7] = {3, 0, 1, 2, 0, 1, 2};
  const float pw[7] = {3.f, 1.f, 1.f, 1.f, -2.f, -2.f, -2.f};

  int tile = blockIdx.x;
  int prod = blockIdx.y;
  int a0 = (tile >> 2) * 128;
  int b0 = (tile & 3) * 128;
  const unsigned char* Abase = nT8 + ((size_t)pa[prod] * DDIM + a0) * N_ROWS;
  const unsigned char* Bbase = nT8 + ((size_t)pb[prod] * DDIM + b0) * N_ROWS;

  int t = threadIdx.x;
  int w = t >> 6;              // 8 waves: 2 (M) x 4 (N) sub-tiles of 64x32
  int lane = t & 63;
  int wr = (w >> 2) * 64;
  int wc = (w & 3) * 32;
  int lm = lane & 15;
  int lq = lane >> 4;

  floatx4 zero = {0.f, 0.f, 0.f, 0.f};
  floatx4 acc[4][2];
#pragma unroll
  for (int mi = 0; mi < 4; ++mi)
#pragma unroll
    for (int ni = 0; ni < 2; ++ni) acc[mi][ni] = zero;

  // 32 chunks of K=128, double-buffered
  stage_tiles(Abase, Bbase, 0, ls[0][0], ls[0][1], w, lane);
  __syncthreads();
  for (int i = 0; i < 15; ++i) {
    int k0 = (2 * i + 1) * 128;
    stage_tiles(Abase, Bbase, k0, ls[1][0], ls[1][1], w, lane);
    compute_tiles(ls[0][0], ls[0][1], acc, wr, wc, lm, lq);
    __syncthreads();
    stage_tiles(Abase, Bbase, k0 + 128, ls[0][0], ls[0][1], w, lane);
    compute_tiles(ls[1][0], ls[1][1], acc, wr, wc, lm, lq);
    __syncthreads();
  }
  stage_tiles(Abase, Bbase, 31 * 128, ls[1][0], ls[1][1], w, lane);
  compute_tiles(ls[0][0], ls[0][1], acc, wr, wc, lm, lq);  // chunk 30
  __syncthreads();
  compute_tiles(ls[1][0], ls[1][1], acc, wr, wc, lm, lq);  // chunk 31

  // Local Frobenius: C/D layout is a bijection -> sum of squares is exact.
  float s = 0.f;
#pragma unroll
  for (int mi = 0; mi < 4; ++mi)
#pragma unroll
    for (int ni = 0; ni < 2; ++ni)
#pragma unroll
      for (int r = 0; r < 4; ++r) {
        float v = acc[mi][ni][r];
        s += v * v;
      }
#pragma unroll
  for (int off = 32; off > 0; off >>= 1) s += __shfl_down(s, off, 64);
  if (lane == 0) red[w] = s;
  __syncthreads();
  if (t == 0) {
    float tot = red[0] + red[1] + red[2] + red[3] + red[4] + red[5] + red[6] +
                red[7];
    atomicAdd(out, pw[prod] * LOSS_SCALE * tot);  // 112 atomics total
  }
}

extern "C" void kernel_launch(void* const* d_in, const int* in_sizes, int n_in,
                              void* d_out, int out_size, void* d_ws, size_t ws_size,
                              hipStream_t stream) {
  const float* in_rgb   = (const float*)d_in[0];
  const float* in_depth = (const float*)d_in[1];
  const float* in_ir    = (const float*)d_in[2];
  const float* in_t     = (const float*)d_in[3];

  unsigned char* nT8 = (unsigned char*)d_ws;  // 8 MB fp8, K-contiguous

  preprocess_kernel<<<dim3(64, 4), 256, 0, stream>>>(
      in_rgb, in_depth, in_ir, in_t, nT8, (float*)d_out);
  gram_frob_kernel<<<dim3(16, 7), 512, 0, stream>>>(nT8, (float*)d_out);
}

// Round 7
// 122.769 us; speedup vs baseline: 1.0158x; 1.0158x over previous
//
#include <hip/hip_runtime.h>
#include <hip/hip_bf16.h>

// loss = (100/N^2) * [3*s_tt + s_rr + s_dd + s_ii - 2*(s_tr + s_td + s_ti)]
// where s_ab = || n_a^T n_b ||_F^2   (n_x = row-normalized input, N=4096, D=512)
//
// fp8 pipeline, 2 dispatches (no memset, no Cbuf, no reduce):
// K1 preprocess: fused rownorm + scale(16/||r||) + fp8 cast + transpose
//                -> nT8[mod][c][k] (8 MB, K-contiguous); also zeroes d_out
// K2 gram:       7 TN-GEMMs 512x512 fp8 as 224 blocks = 7 x (8x4) tiles of
//                64x128 (N-SPLIT, full K per block -- Frobenius decomposes
//                over tiles, not K), K-chunk 128, dbuf 48 KB LDS, XOR swizzle,
//                b128 conflict-free frag reads, local Frobenius -> 1 atomic.
// Frobenius structure => immune to any consistent K-permutation and to the
// MFMA C/D layout; x16 pre-scale folded into normalization, /16^4 at the end.

typedef __attribute__((ext_vector_type(4))) float floatx4;
typedef __attribute__((ext_vector_type(8))) unsigned short ushort8;
typedef __attribute__((ext_vector_type(2))) long long llx2;

#define N_ROWS 4096
#define DDIM   512
// 100 / (4096^2 * 16^4)
#define LOSS_SCALE 9.094947017729282e-11f

__device__ __forceinline__ const float* sel_mod(int mod, const float* a,
                                                const float* b, const float* c,
                                                const float* d) {
  return mod == 0 ? a : mod == 1 ? b : mod == 2 ? c : d;
}

__global__ __launch_bounds__(256) void preprocess_kernel(
    const float* __restrict__ in0, const float* __restrict__ in1,
    const float* __restrict__ in2, const float* __restrict__ in3,
    unsigned char* __restrict__ nT8, float* __restrict__ out) {
  // grid: x = 64 (k-strips of 64 rows), y = 4 (mod). 256 threads = 4 waves.
  int mod = blockIdx.y;
  int k0 = blockIdx.x * 64;
  const float* X = sel_mod(mod, in0, in1, in2, in3) + (size_t)k0 * DDIM;

  if (blockIdx.x == 0 && blockIdx.y == 0 && threadIdx.x == 0)
    out[0] = 0.f;  // d_out is re-poisoned before every call; gram accumulates

  __shared__ float rsc[64];
  __shared__ unsigned short tile[128][72];  // bf16 intermediate, 16B-aligned

  int t = threadIdx.x;
  int w = t >> 6, lane = t & 63;

  // phase A: row norms for this strip (16 rows per wave)
#pragma unroll
  for (int i = 0; i < 16; ++i) {
    int r = w * 16 + i;
    const float4* rp = (const float4*)(X + (size_t)r * DDIM);
    float4 a = rp[lane];
    float4 b = rp[lane + 64];
    float ss = a.x * a.x + a.y * a.y + a.z * a.z + a.w * a.w +
               b.x * b.x + b.y * b.y + b.z * b.z + b.w * b.w;
#pragma unroll
    for (int off = 32; off > 0; off >>= 1) ss += __shfl_down(ss, off, 64);
    if (lane == 0) rsc[r] = 16.0f / fmaxf(sqrtf(ss), 1e-12f);  // x16 folded
  }
  __syncthreads();

  // phase B: 4 panels of 128 cols; rows re-read from L2
  for (int p = 0; p < 4; ++p) {
#pragma unroll
    for (int it = 0; it < 8; ++it) {
      int idx = it * 256 + t;
      int r = idx >> 5;          // k-row 0..63
      int c4 = idx & 31;         // float4 index within 128-col panel
      float4 v = ((const float4*)(X + (size_t)r * DDIM + p * 128))[c4];
      float sc = rsc[r];
      __hip_bfloat16 h0 = __float2bfloat16(v.x * sc);
      __hip_bfloat16 h1 = __float2bfloat16(v.y * sc);
      __hip_bfloat16 h2 = __float2bfloat16(v.z * sc);
      __hip_bfloat16 h3 = __float2bfloat16(v.w * sc);
      tile[c4 * 4 + 0][r] = *(unsigned short*)&h0;
      tile[c4 * 4 + 1][r] = *(unsigned short*)&h1;
      tile[c4 * 4 + 2][r] = *(unsigned short*)&h2;
      tile[c4 * 4 + 3][r] = *(unsigned short*)&h3;
    }
    __syncthreads();
#pragma unroll
    for (int it = 0; it < 2; ++it) {
      int idx = it * 256 + t;
      int c = idx >> 2;          // column 0..127
      int g = idx & 3;           // 16-byte k-group
      ushort8 u0 = *(const ushort8*)&tile[c][g * 16];
      ushort8 u1 = *(const ushort8*)&tile[c][g * 16 + 8];
      float f[16];
#pragma unroll
      for (int j = 0; j < 8; ++j) {
        f[j] = __uint_as_float(((unsigned int)(unsigned short)u0[j]) << 16);
        f[8 + j] = __uint_as_float(((unsigned int)(unsigned short)u1[j]) << 16);
      }
      unsigned int wds[4];
#pragma unroll
      for (int q = 0; q < 4; ++q) {
        unsigned int pk =
            __builtin_amdgcn_cvt_pk_fp8_f32(f[4 * q], f[4 * q + 1], 0, 0);
        pk = __builtin_amdgcn_cvt_pk_fp8_f32(f[4 * q + 2], f[4 * q + 3], pk, 1);
        wds[q] = pk;  // byte order is a fixed uniform k-perm: harmless
      }
      uint4 o = {wds[0], wds[1], wds[2], wds[3]};
      *(uint4*)(nT8 + ((size_t)(mod * DDIM + p * 128 + c)) * N_ROWS + k0 +
                g * 16) = o;
    }
    __syncthreads();
  }
}

__device__ __forceinline__ void stage_tiles(
    const unsigned char* __restrict__ Abase,
    const unsigned char* __restrict__ Bbase, int k0,
    unsigned char* ls, int w, int lane) {
  // Stages A (64 local rows, LDS 0..8191) + B (128 local rows, LDS 8192..24575)
  // 16B-chunk XOR swizzle on the GLOBAL side: LDS slot s of local row r holds
  // global chunk s ^ ((r>>1)&7); LDS side is the natural wave-uniform
  // base + lane*16 required by global_load_lds.
  int rr = lane >> 3;          // row 0..7 within the 8-row staging group
  int s = lane & 7;            // 16B slot within 128B row
  // A rows: 2 rounds x (4 waves x 8 rows) = 64
#pragma unroll
  for (int c = 0; c < 2; ++c) {
    int base = c * 32 + w * 8;  // wave-uniform
    int row = base + rr;
    int gc = s ^ ((row >> 1) & 7);
    const unsigned char* ga = Abase + (size_t)row * N_ROWS + k0 + gc * 16;
    __builtin_amdgcn_global_load_lds(
        (__attribute__((address_space(1))) void*)(void*)ga,
        (__attribute__((address_space(3))) void*)(void*)&ls[base * 128],
        16, 0, 0);
  }
  // B rows: 4 rounds x 32 = 128
#pragma unroll
  for (int c = 0; c < 4; ++c) {
    int base = c * 32 + w * 8;  // wave-uniform
    int row = base + rr;
    int gc = s ^ ((row >> 1) & 7);
    const unsigned char* gb = Bbase + (size_t)row * N_ROWS + k0 + gc * 16;
    __builtin_amdgcn_global_load_lds(
        (__attribute__((address_space(1))) void*)(void*)gb,
        (__attribute__((address_space(3))) void*)(void*)&ls[8192 + base * 128],
        16, 0, 0);
  }
}

__device__ __forceinline__ void compute_tiles(
    const unsigned char* ls, floatx4 acc[2][4], int wm, int wn, int lm,
    int lq) {
  // Lane lq's 4 K-steps live in LDS slots lq*2, lq*2+1 (after unswizzle):
  // two b128 reads per fragment row (conflict-free, uniform 2 lanes/bank).
  // (ks,lq) -> global K-unit lq*4 + (ks>>1)*2 + (ks&1): a uniform K-perm
  // applied identically to A and B => Frobenius-invariant.
  llx2 A16[2][2], B16[4][2];
#pragma unroll
  for (int mi = 0; mi < 2; ++mi) {
    int row = wm + mi * 16 + lm;            // local A row 0..63
    int sw = (row >> 1) & 7;
    A16[mi][0] = *(const llx2*)&ls[row * 128 + ((lq * 2) ^ sw) * 16];
    A16[mi][1] = *(const llx2*)&ls[row * 128 + ((lq * 2 + 1) ^ sw) * 16];
  }
#pragma unroll
  for (int ni = 0; ni < 4; ++ni) {
    int row = wn + ni * 16 + lm;            // local B row 0..127
    int sw = (row >> 1) & 7;
    B16[ni][0] = *(const llx2*)&ls[8192 + row * 128 + ((lq * 2) ^ sw) * 16];
    B16[ni][1] =
        *(const llx2*)&ls[8192 + row * 128 + ((lq * 2 + 1) ^ sw) * 16];
  }
#pragma unroll
  for (int ks = 0; ks < 4; ++ks) {
    int h = ks >> 1, e = ks & 1;
#pragma unroll
    for (int mi = 0; mi < 2; ++mi)
#pragma unroll
      for (int ni = 0; ni < 4; ++ni)
        acc[mi][ni] = __builtin_amdgcn_mfma_f32_16x16x32_fp8_fp8(
            A16[mi][h][e], B16[ni][h][e], acc[mi][ni], 0, 0, 0);
  }
}

__global__ __launch_bounds__(256) void gram_frob_kernel(
    const unsigned char* __restrict__ nT8, float* __restrict__ out) {
  // blockIdx.x = tile 0..31 (A-strip 0..7 x B-strip 0..3), .y = product 0..6
  __shared__ unsigned char ls[2][24576];  // [buf][A(8K)+B(16K)] = 48 KB
  __shared__ float red[4];

  const int   pa[7] = {3, 0, 1, 2, 3, 3, 3};
  const int   pb[7] = {3, 0, 1, 2, 0, 1, 2};
  const float pw[7] = {3.f, 1.f, 1.f, 1.f, -2.f, -2.f, -2.f};

  int prod = blockIdx.y;
  int a0 = (blockIdx.x >> 2) * 64;    // 8 A-strips of 64
  int b0 = (blockIdx.x & 3) * 128;    // 4 B-strips of 128
  const unsigned char* Abase = nT8 + ((size_t)pa[prod] * DDIM + a0) * N_ROWS;
  const unsigned char* Bbase = nT8 + ((size_t)pb[prod] * DDIM + b0) * N_ROWS;

  int t = threadIdx.x;
  int w = t >> 6;              // 4 waves: 2 (M) x 2 (N) sub-tiles of 32x64
  int lane = t & 63;
  int wm = (w >> 1) * 32;
  int wn = (w & 1) * 64;
  int lm = lane & 15;
  int lq = lane >> 4;

  floatx4 zero = {0.f, 0.f, 0.f, 0.f};
  floatx4 acc[2][4];
#pragma unroll
  for (int mi = 0; mi < 2; ++mi)
#pragma unroll
    for (int ni = 0; ni < 4; ++ni) acc[mi][ni] = zero;

  // 32 chunks of K=128, double-buffered
  stage_tiles(Abase, Bbase, 0, ls[0], w, lane);
  __syncthreads();
  for (int i = 0; i < 15; ++i) {
    int k0 = (2 * i + 1) * 128;
    stage_tiles(Abase, Bbase, k0, ls[1], w, lane);
    compute_tiles(ls[0], acc, wm, wn, lm, lq);
    __syncthreads();
    stage_tiles(Abase, Bbase, k0 + 128, ls[0], w, lane);
    compute_tiles(ls[1], acc, wm, wn, lm, lq);
    __syncthreads();
  }
  stage_tiles(Abase, Bbase, 31 * 128, ls[1], w, lane);
  compute_tiles(ls[0], acc, wm, wn, lm, lq);  // chunk 30
  __syncthreads();
  compute_tiles(ls[1], acc, wm, wn, lm, lq);  // chunk 31

  // Local Frobenius: C/D layout is a bijection -> sum of squares is exact.
  float s = 0.f;
#pragma unroll
  for (int mi = 0; mi < 2; ++mi)
#pragma unroll
    for (int ni = 0; ni < 4; ++ni)
#pragma unroll
      for (int r = 0; r < 4; ++r) {
        float v = acc[mi][ni][r];
        s += v * v;
      }
#pragma unroll
  for (int off = 32; off > 0; off >>= 1) s += __shfl_down(s, off, 64);
  if (lane == 0) red[w] = s;
  __syncthreads();
  if (t == 0) {
    float tot = red[0] + red[1] + red[2] + red[3];
    atomicAdd(out, pw[prod] * LOSS_SCALE * tot);  // 224 atomics total
  }
}

extern "C" void kernel_launch(void* const* d_in, const int* in_sizes, int n_in,
                              void* d_out, int out_size, void* d_ws, size_t ws_size,
                              hipStream_t stream) {
  const float* in_rgb   = (const float*)d_in[0];
  const float* in_depth = (const float*)d_in[1];
  const float* in_ir    = (const float*)d_in[2];
  const float* in_t     = (const float*)d_in[3];

  unsigned char* nT8 = (unsigned char*)d_ws;  // 8 MB fp8, K-contiguous

  preprocess_kernel<<<dim3(64, 4), 256, 0, stream>>>(
      in_rgb, in_depth, in_ir, in_t, nT8, (float*)d_out);
  gram_frob_kernel<<<dim3(32, 7), 256, 0, stream>>>(nT8, (float*)d_out);
}

// Round 9
// 119.307 us; speedup vs baseline: 1.0452x; 1.0290x over previous
//
#include <hip/hip_runtime.h>
#include <hip/hip_bf16.h>

// loss = (100/N^2) * [3*s_tt + s_rr + s_dd + s_ii - 2*(s_tr + s_td + s_ti)]
// where s_ab = || n_a^T n_b ||_F^2   (n_x = row-normalized input, N=4096, D=512)
//
// fp8 pipeline, 2 dispatches (no memset, no Cbuf, no reduce):
// K1 preprocess: fused rownorm + scale(16/||r||) + fp8 cast + transpose
//                -> nT8[mod][c][k] (8 MB, K-contiguous); also zeroes d_out
// K2 gram:       7 TN-GEMMs 512x512 fp8 as 448 blocks = 7 x (8x8) tiles of
//                64x64 (N-SPLIT, full K per block -- Frobenius is local per
//                tile), K-chunk 128, dbuf 32 KB LDS, XOR swizzle, b128
//                conflict-free frag reads, local Frobenius -> 1 atomic/block.
// Frobenius structure => immune to any consistent K-permutation and to the
// MFMA C/D layout; x16 pre-scale folded into normalization, /16^4 at the end.

typedef __attribute__((ext_vector_type(4))) float floatx4;
typedef __attribute__((ext_vector_type(8))) unsigned short ushort8;
typedef __attribute__((ext_vector_type(2))) long long llx2;

#define N_ROWS 4096
#define DDIM   512
// 100 / (4096^2 * 16^4)
#define LOSS_SCALE 9.094947017729282e-11f

__device__ __forceinline__ const float* sel_mod(int mod, const float* a,
                                                const float* b, const float* c,
                                                const float* d) {
  return mod == 0 ? a : mod == 1 ? b : mod == 2 ? c : d;
}

__global__ __launch_bounds__(256) void preprocess_kernel(
    const float* __restrict__ in0, const float* __restrict__ in1,
    const float* __restrict__ in2, const float* __restrict__ in3,
    unsigned char* __restrict__ nT8, float* __restrict__ out) {
  // grid: x = 64 (k-strips of 64 rows), y = 4 (mod). 256 threads = 4 waves.
  int mod = blockIdx.y;
  int k0 = blockIdx.x * 64;
  const float* X = sel_mod(mod, in0, in1, in2, in3) + (size_t)k0 * DDIM;

  if (blockIdx.x == 0 && blockIdx.y == 0 && threadIdx.x == 0)
    out[0] = 0.f;  // d_out re-poisoned each call; gram (next dispatch) accums

  __shared__ float rsc[64];
  __shared__ unsigned short tile[128][72];  // bf16 intermediate, 16B-aligned

  int t = threadIdx.x;
  int w = t >> 6, lane = t & 63;

  // phase A: row norms for this strip (16 rows per wave)
#pragma unroll
  for (int i = 0; i < 16; ++i) {
    int r = w * 16 + i;
    const float4* rp = (const float4*)(X + (size_t)r * DDIM);
    float4 a = rp[lane];
    float4 b = rp[lane + 64];
    float ss = a.x * a.x + a.y * a.y + a.z * a.z + a.w * a.w +
               b.x * b.x + b.y * b.y + b.z * b.z + b.w * b.w;
#pragma unroll
    for (int off = 32; off > 0; off >>= 1) ss += __shfl_down(ss, off, 64);
    if (lane == 0) rsc[r] = 16.0f / fmaxf(sqrtf(ss), 1e-12f);  // x16 folded
  }
  __syncthreads();

  // phase B: 4 panels of 128 cols; rows re-read from L2
  for (int p = 0; p < 4; ++p) {
#pragma unroll
    for (int it = 0; it < 8; ++it) {
      int idx = it * 256 + t;
      int r = idx >> 5;          // k-row 0..63
      int c4 = idx & 31;         // float4 index within 128-col panel
      float4 v = ((const float4*)(X + (size_t)r * DDIM + p * 128))[c4];
      float sc = rsc[r];
      __hip_bfloat16 h0 = __float2bfloat16(v.x * sc);
      __hip_bfloat16 h1 = __float2bfloat16(v.y * sc);
      __hip_bfloat16 h2 = __float2bfloat16(v.z * sc);
      __hip_bfloat16 h3 = __float2bfloat16(v.w * sc);
      tile[c4 * 4 + 0][r] = *(unsigned short*)&h0;
      tile[c4 * 4 + 1][r] = *(unsigned short*)&h1;
      tile[c4 * 4 + 2][r] = *(unsigned short*)&h2;
      tile[c4 * 4 + 3][r] = *(unsigned short*)&h3;
    }
    __syncthreads();
#pragma unroll
    for (int it = 0; it < 2; ++it) {
      int idx = it * 256 + t;
      int c = idx >> 2;          // column 0..127
      int g = idx & 3;           // 16-byte k-group
      ushort8 u0 = *(const ushort8*)&tile[c][g * 16];
      ushort8 u1 = *(const ushort8*)&tile[c][g * 16 + 8];
      float f[16];
#pragma unroll
      for (int j = 0; j < 8; ++j) {
        f[j] = __uint_as_float(((unsigned int)(unsigned short)u0[j]) << 16);
        f[8 + j] = __uint_as_float(((unsigned int)(unsigned short)u1[j]) << 16);
      }
      unsigned int wds[4];
#pragma unroll
      for (int q = 0; q < 4; ++q) {
        unsigned int pk =
            __builtin_amdgcn_cvt_pk_fp8_f32(f[4 * q], f[4 * q + 1], 0, 0);
        pk = __builtin_amdgcn_cvt_pk_fp8_f32(f[4 * q + 2], f[4 * q + 3], pk, 1);
        wds[q] = pk;  // byte order is a fixed uniform k-perm: harmless
      }
      uint4 o = {wds[0], wds[1], wds[2], wds[3]};
      *(uint4*)(nT8 + ((size_t)(mod * DDIM + p * 128 + c)) * N_ROWS + k0 +
                g * 16) = o;
    }
    __syncthreads();
  }
}

__device__ __forceinline__ void stage_tiles(
    const unsigned char* __restrict__ Abase,
    const unsigned char* __restrict__ Bbase, int k0,
    unsigned char* ls, int w, int lane) {
  // A: 64 local rows at ls[0..8191]; B: 64 local rows at ls[8192..16383].
  // 16B-chunk XOR swizzle on the GLOBAL side: LDS slot s of local row r holds
  // global chunk s ^ ((r>>1)&7); LDS side is the wave-uniform base + lane*16
  // required by global_load_lds.
  int rr = lane >> 3;          // row 0..7 within the 8-row staging group
  int s = lane & 7;            // 16B slot within 128B row
#pragma unroll
  for (int c = 0; c < 2; ++c) {
    int base = c * 32 + w * 8;  // wave-uniform; 2 x (4 waves x 8 rows) = 64
    int row = base + rr;
    int gc = s ^ ((row >> 1) & 7);
    const unsigned char* ga = Abase + (size_t)row * N_ROWS + k0 + gc * 16;
    __builtin_amdgcn_global_load_lds(
        (__attribute__((address_space(1))) void*)(void*)ga,
        (__attribute__((address_space(3))) void*)(void*)&ls[base * 128],
        16, 0, 0);
  }
#pragma unroll
  for (int c = 0; c < 2; ++c) {
    int base = c * 32 + w * 8;
    int row = base + rr;
    int gc = s ^ ((row >> 1) & 7);
    const unsigned char* gb = Bbase + (size_t)row * N_ROWS + k0 + gc * 16;
    __builtin_amdgcn_global_load_lds(
        (__attribute__((address_space(1))) void*)(void*)gb,
        (__attribute__((address_space(3))) void*)(void*)&ls[8192 + base * 128],
        16, 0, 0);
  }
}

__device__ __forceinline__ void compute_tiles(
    const unsigned char* ls, floatx4 acc[2][2], int wm, int wn, int lm,
    int lq) {
  // Lane lq's 4 K-steps live in LDS slots lq*2, lq*2+1 (after unswizzle):
  // two b128 reads per fragment row (conflict-free, uniform 2 lanes/bank).
  // (ks,lq) -> global K-unit lq*4 + (ks>>1)*2 + (ks&1): a uniform K-perm
  // applied identically to A and B => Frobenius-invariant.
  llx2 A16[2][2], B16[2][2];
#pragma unroll
  for (int mi = 0; mi < 2; ++mi) {
    int row = wm + mi * 16 + lm;            // local A row 0..63
    int sw = (row >> 1) & 7;
    A16[mi][0] = *(const llx2*)&ls[row * 128 + ((lq * 2) ^ sw) * 16];
    A16[mi][1] = *(const llx2*)&ls[row * 128 + ((lq * 2 + 1) ^ sw) * 16];
  }
#pragma unroll
  for (int ni = 0; ni < 2; ++ni) {
    int row = wn + ni * 16 + lm;            // local B row 0..63
    int sw = (row >> 1) & 7;
    B16[ni][0] = *(const llx2*)&ls[8192 + row * 128 + ((lq * 2) ^ sw) * 16];
    B16[ni][1] =
        *(const llx2*)&ls[8192 + row * 128 + ((lq * 2 + 1) ^ sw) * 16];
  }
#pragma unroll
  for (int ks = 0; ks < 4; ++ks) {
    int h = ks >> 1, e = ks & 1;
#pragma unroll
    for (int mi = 0; mi < 2; ++mi)
#pragma unroll
      for (int ni = 0; ni < 2; ++ni)
        acc[mi][ni] = __builtin_amdgcn_mfma_f32_16x16x32_fp8_fp8(
            A16[mi][h][e], B16[ni][h][e], acc[mi][ni], 0, 0, 0);
  }
}

__global__ __launch_bounds__(256) void gram_frob_kernel(
    const unsigned char* __restrict__ nT8, float* __restrict__ out) {
  // blockIdx.x = tile 0..63 (8x8 of 64x64 over 512x512), .y = product 0..6
  __shared__ __align__(16) unsigned char ls[2][16384];  // dbuf, 32 KB total
  __shared__ float red[4];

  const int   pa[7] = {3, 0, 1, 2, 3, 3, 3};
  const int   pb[7] = {3, 0, 1, 2, 0, 1, 2};
  const float pw[7] = {3.f, 1.f, 1.f, 1.f, -2.f, -2.f, -2.f};

  int prod = blockIdx.y;
  int a0 = (blockIdx.x >> 3) * 64;    // 8 A-strips of 64
  int b0 = (blockIdx.x & 7) * 64;     // 8 B-strips of 64
  const unsigned char* Abase = nT8 + ((size_t)pa[prod] * DDIM + a0) * N_ROWS;
  const unsigned char* Bbase = nT8 + ((size_t)pb[prod] * DDIM + b0) * N_ROWS;

  int t = threadIdx.x;
  int w = t >> 6;              // 4 waves: 2 (M) x 2 (N) sub-tiles of 32x32
  int lane = t & 63;
  int wm = (w >> 1) * 32;
  int wn = (w & 1) * 32;
  int lm = lane & 15;
  int lq = lane >> 4;

  floatx4 zero = {0.f, 0.f, 0.f, 0.f};
  floatx4 acc[2][2];
#pragma unroll
  for (int mi = 0; mi < 2; ++mi)
#pragma unroll
    for (int ni = 0; ni < 2; ++ni) acc[mi][ni] = zero;

  // 32 chunks of K=128, double-buffered
  stage_tiles(Abase, Bbase, 0, ls[0], w, lane);
  __syncthreads();
  for (int i = 0; i < 15; ++i) {
    int k0 = (2 * i + 1) * 128;
    stage_tiles(Abase, Bbase, k0, ls[1], w, lane);
    compute_tiles(ls[0], acc, wm, wn, lm, lq);
    __syncthreads();
    stage_tiles(Abase, Bbase, k0 + 128, ls[0], w, lane);
    compute_tiles(ls[1], acc, wm, wn, lm, lq);
    __syncthreads();
  }
  stage_tiles(Abase, Bbase, 31 * 128, ls[1], w, lane);
  compute_tiles(ls[0], acc, wm, wn, lm, lq);  // chunk 30
  __syncthreads();
  compute_tiles(ls[1], acc, wm, wn, lm, lq);  // chunk 31

  // Local Frobenius: C/D layout is a bijection -> sum of squares is exact.
  float s = 0.f;
#pragma unroll
  for (int mi = 0; mi < 2; ++mi)
#pragma unroll
    for (int ni = 0; ni < 2; ++ni)
#pragma unroll
      for (int r = 0; r < 4; ++r) {
        float v = acc[mi][ni][r];
        s += v * v;
      }
#pragma unroll
  for (int off = 32; off > 0; off >>= 1) s += __shfl_down(s, off, 64);
  if (lane == 0) red[w] = s;
  __syncthreads();
  if (t == 0) {
    float tot = red[0] + red[1] + red[2] + red[3];
    atomicAdd(out, pw[prod] * LOSS_SCALE * tot);  // 448 atomics total
  }
}

extern "C" void kernel_launch(void* const* d_in, const int* in_sizes, int n_in,
                              void* d_out, int out_size, void* d_ws, size_t ws_size,
                              hipStream_t stream) {
  const float* in_rgb   = (const float*)d_in[0];
  const float* in_depth = (const float*)d_in[1];
  const float* in_ir    = (const float*)d_in[2];
  const float* in_t     = (const float*)d_in[3];

  unsigned char* nT8 = (unsigned char*)d_ws;  // 8 MB fp8, K-contiguous

  preprocess_kernel<<<dim3(64, 4), 256, 0, stream>>>(
      in_rgb, in_depth, in_ir, in_t, nT8, (float*)d_out);
  gram_frob_kernel<<<dim3(64, 7), 256, 0, stream>>>(nT8, (float*)d_out);
}